// Round 6
// baseline (229.848 us; speedup 1.0000x reference)
//
#include <hip/hip_runtime.h>

#define IN_CH 96
#define OUT_CH 384
#define THREADS 384

typedef float f32x4 __attribute__((ext_vector_type(4)));

// R4 base (proven 114.8us), two isolated edits:
//  1. PLAIN stores (the harness fill kernels sustain 6.9 TB/s with plain
//     stores; nt/no-allocate bypasses L2 write aggregation on the 403MB
//     write stream that dominates our traffic).
//  2. #pragma unroll 2 on the grid-stride loop: compiler-managed 2-deep
//     iteration overlap (2x loads in flight) WITHOUT hand-held ping-pong
//     registers (R5's hand pipeline overflowed the 102-VGPR cap -> spills).
//
// Thread t: channel-group cg = t%96 (4 consecutive output channels of joint
// cg>>2), row lane rl = t/96 (row 4q+rl). 12-float contiguous x-window
// (3x dwordx4, overlap served by L1), 48 FMAs, one float4 store.
__global__ __launch_bounds__(THREADS, 5) void skel_linear_kernel(
    const float* __restrict__ x,
    const float* __restrict__ weight,
    const float* __restrict__ mask,
    const float* __restrict__ bias,
    float* __restrict__ out,
    int batch)
{
    const int t     = threadIdx.x;
    const int cg    = t % 96;
    const int rl    = t / 96;          // 0..3
    const int chan  = cg * 4;
    const int joint = cg >> 2;
    const int jc    = (joint - 1 < 0) ? 0 : ((joint - 1 > 21) ? 21 : joint - 1);
    const int c0    = jc * 4;          // contiguous 12-col window [c0, c0+12)

    // Hoist masked weights + bias into registers (once per launch).
    float w[4][12];
    float b[4];
#pragma unroll
    for (int j = 0; j < 4; ++j) {
        const size_t row = (size_t)(chan + j) * IN_CH;
#pragma unroll
        for (int c = 0; c < 12; ++c)
            w[j][c] = weight[row + c0 + c] * mask[row + c0 + c];
        b[j] = bias[chan + j];
    }

    const int nquads = batch >> 2;     // 65536 row-quads
#pragma unroll 2
    for (int q = blockIdx.x; q < nquads; q += gridDim.x) {
        const int row = q * 4 + rl;
        const f32x4* xv = reinterpret_cast<const f32x4*>(x + (size_t)row * IN_CH + c0);
        const f32x4 xa = xv[0];
        const f32x4 xb = xv[1];
        const f32x4 xc = xv[2];

        f32x4 o4;
#pragma unroll
        for (int j = 0; j < 4; ++j) {
            float acc = b[j];
            acc = fmaf(w[j][0],  xa.x, acc);
            acc = fmaf(w[j][1],  xa.y, acc);
            acc = fmaf(w[j][2],  xa.z, acc);
            acc = fmaf(w[j][3],  xa.w, acc);
            acc = fmaf(w[j][4],  xb.x, acc);
            acc = fmaf(w[j][5],  xb.y, acc);
            acc = fmaf(w[j][6],  xb.z, acc);
            acc = fmaf(w[j][7],  xb.w, acc);
            acc = fmaf(w[j][8],  xc.x, acc);
            acc = fmaf(w[j][9],  xc.y, acc);
            acc = fmaf(w[j][10], xc.z, acc);
            acc = fmaf(w[j][11], xc.w, acc);
            o4[j] = acc;
        }

        f32x4* dst = reinterpret_cast<f32x4*>(
            out + (size_t)row * OUT_CH + chan);
        *dst = o4;                       // plain store: L2-aggregated writeback
    }
}

extern "C" void kernel_launch(void* const* d_in, const int* in_sizes, int n_in,
                              void* d_out, int out_size, void* d_ws, size_t ws_size,
                              hipStream_t stream) {
    const float* x      = (const float*)d_in[0];
    const float* weight = (const float*)d_in[1];
    const float* mask   = (const float*)d_in[2];
    const float* bias   = (const float*)d_in[3];
    float* out          = (float*)d_out;

    const int batch = in_sizes[0] / IN_CH;   // 262144
    const int grid  = 768;   // 256 CUs x 3 resident blocks (6 waves, ~90 VGPR)

    skel_linear_kernel<<<grid, THREADS, 0, stream>>>(x, weight, mask, bias, out, batch);
}

// Round 7
// 125.338 us; speedup vs baseline: 1.8338x; 1.8338x over previous
//
#include <hip/hip_runtime.h>

#define IN_CH 96
#define OUT_CH 384
#define THREADS 384

typedef float f32x4 __attribute__((ext_vector_type(4)));

// R4 base (proven 114.8us @ grid 768 = 3 blocks/CU) with ONE change:
// grid 1280 = 5 resident blocks/CU = 30/32 waves/CU. R6's counters showed
// VGPR=40 (grid-limited occupancy, not register-limited) and the per-iter
// time (~3240 cy) is ~6x the VALU work -> latency-bound, needs more waves.
// nt stores kept: A/B across R4/R5/R6 shows nt = 114.8us vs plain = 212-230us
// for this 403MB write-once stream (no-allocate streaming avoids L2 thrash).
//
// Thread t: channel-group cg = t%96 (4 consecutive output channels of joint
// cg>>2), row lane rl = t/96 (row 4q+rl). 12-float contiguous x-window
// (3x dwordx4, 3x overlap served by L1/L2), 48 FMAs, one float4 nt store.
__global__ __launch_bounds__(THREADS, 5) void skel_linear_kernel(
    const float* __restrict__ x,
    const float* __restrict__ weight,
    const float* __restrict__ mask,
    const float* __restrict__ bias,
    float* __restrict__ out,
    int batch)
{
    const int t     = threadIdx.x;
    const int cg    = t % 96;
    const int rl    = t / 96;          // 0..3
    const int chan  = cg * 4;
    const int joint = cg >> 2;
    const int jc    = (joint - 1 < 0) ? 0 : ((joint - 1 > 21) ? 21 : joint - 1);
    const int c0    = jc * 4;          // contiguous 12-col window [c0, c0+12)

    // Hoist masked weights + bias into registers (once per launch).
    float w[4][12];
    float b[4];
#pragma unroll
    for (int j = 0; j < 4; ++j) {
        const size_t row = (size_t)(chan + j) * IN_CH;
#pragma unroll
        for (int c = 0; c < 12; ++c)
            w[j][c] = weight[row + c0 + c] * mask[row + c0 + c];
        b[j] = bias[chan + j];
    }

    const int nquads = batch >> 2;     // 65536 row-quads
    for (int q = blockIdx.x; q < nquads; q += gridDim.x) {
        const int row = q * 4 + rl;
        const f32x4* xv = reinterpret_cast<const f32x4*>(x + (size_t)row * IN_CH + c0);
        const f32x4 xa = xv[0];
        const f32x4 xb = xv[1];
        const f32x4 xc = xv[2];

        f32x4 o4;
#pragma unroll
        for (int j = 0; j < 4; ++j) {
            float acc = b[j];
            acc = fmaf(w[j][0],  xa.x, acc);
            acc = fmaf(w[j][1],  xa.y, acc);
            acc = fmaf(w[j][2],  xa.z, acc);
            acc = fmaf(w[j][3],  xa.w, acc);
            acc = fmaf(w[j][4],  xb.x, acc);
            acc = fmaf(w[j][5],  xb.y, acc);
            acc = fmaf(w[j][6],  xb.z, acc);
            acc = fmaf(w[j][7],  xb.w, acc);
            acc = fmaf(w[j][8],  xc.x, acc);
            acc = fmaf(w[j][9],  xc.y, acc);
            acc = fmaf(w[j][10], xc.z, acc);
            acc = fmaf(w[j][11], xc.w, acc);
            o4[j] = acc;
        }

        f32x4* dst = reinterpret_cast<f32x4*>(
            out + (size_t)row * OUT_CH + chan);
        __builtin_nontemporal_store(o4, dst);   // 16B/lane, wave covers 1KB contiguous
    }
}

extern "C" void kernel_launch(void* const* d_in, const int* in_sizes, int n_in,
                              void* d_out, int out_size, void* d_ws, size_t ws_size,
                              hipStream_t stream) {
    const float* x      = (const float*)d_in[0];
    const float* weight = (const float*)d_in[1];
    const float* mask   = (const float*)d_in[2];
    const float* bias   = (const float*)d_in[3];
    float* out          = (float*)d_out;

    const int batch = in_sizes[0] / IN_CH;   // 262144
    // 1280 = 256 CUs x 5 resident blocks (30/32 waves/CU). R4 was 768 (18
    // waves/CU) and latency-bound; occupancy is the isolated change here.
    const int grid = 1280;

    skel_linear_kernel<<<grid, THREADS, 0, stream>>>(x, weight, mask, bias, out, batch);
}

// Round 8
// 106.988 us; speedup vs baseline: 2.1483x; 1.1715x over previous
//
#include <hip/hip_runtime.h>

#define IN_CH 96
#define OUT_CH 384
#define THREADS 384

typedef float f32x4 __attribute__((ext_vector_type(4)));
typedef float f32x2 __attribute__((ext_vector_type(2)));

// R4 winner (nt stores, grid 768, barrier-free) with ONE structural change:
// 2 output channels per thread instead of 4. R7's counters showed VGPR=44 —
// too few for the 4-channel variant's 48-float weight stash, i.e. the
// compiler SANK the loop-invariant weight*mask loads back into the hot loop
// (remat heuristic) and every iteration re-fetched weights. With 24+2 floats
// the stash fits comfortably; an empty asm redefinition makes each value
// opaque so the compiler CANNOT rematerialize the loads inside the loop.
//
// Thread t: p = t%192 -> channels {2p,2p+1} of joint p>>3; rl = t/192 ->
// row 2q+rl. 12-float contiguous x-window (3x dwordx4, overlap via L1),
// 24 FMAs, one f32x2 nt store (wave = 512B contiguous).
__global__ __launch_bounds__(THREADS, 5) void skel_linear_kernel(
    const float* __restrict__ x,
    const float* __restrict__ weight,
    const float* __restrict__ mask,
    const float* __restrict__ bias,
    float* __restrict__ out,
    int batch)
{
    const int t     = threadIdx.x;
    const int p     = t % 192;         // channel-pair index 0..191
    const int rl    = t / 192;         // 0..1
    const int chan  = p * 2;
    const int joint = p >> 3;
    const int jc    = (joint - 1 < 0) ? 0 : ((joint - 1 > 21) ? 21 : joint - 1);
    const int c0    = jc * 4;          // contiguous 12-col window [c0, c0+12)

    // Masked weights + bias, loaded once.
    float w[2][12];
    float b[2];
#pragma unroll
    for (int j = 0; j < 2; ++j) {
        const size_t row = (size_t)(chan + j) * IN_CH;
#pragma unroll
        for (int c = 0; c < 12; ++c)
            w[j][c] = weight[row + c0 + c] * mask[row + c0 + c];
        b[j] = bias[chan + j];
    }
    // Pin the stash in VGPRs: opaque redefinition -> no remat/sinking.
#pragma unroll
    for (int j = 0; j < 2; ++j) {
#pragma unroll
        for (int c = 0; c < 12; ++c)
            asm volatile("" : "+v"(w[j][c]));
        asm volatile("" : "+v"(b[j]));
    }

    const int npairs = batch >> 1;     // 131072 row-pairs
    for (int q = blockIdx.x; q < npairs; q += gridDim.x) {
        const int row = q * 2 + rl;
        const f32x4* xv = reinterpret_cast<const f32x4*>(x + (size_t)row * IN_CH + c0);
        const f32x4 xa = xv[0];
        const f32x4 xb = xv[1];
        const f32x4 xc = xv[2];

        f32x2 o2;
#pragma unroll
        for (int j = 0; j < 2; ++j) {
            float acc = b[j];
            acc = fmaf(w[j][0],  xa.x, acc);
            acc = fmaf(w[j][1],  xa.y, acc);
            acc = fmaf(w[j][2],  xa.z, acc);
            acc = fmaf(w[j][3],  xa.w, acc);
            acc = fmaf(w[j][4],  xb.x, acc);
            acc = fmaf(w[j][5],  xb.y, acc);
            acc = fmaf(w[j][6],  xb.z, acc);
            acc = fmaf(w[j][7],  xb.w, acc);
            acc = fmaf(w[j][8],  xc.x, acc);
            acc = fmaf(w[j][9],  xc.y, acc);
            acc = fmaf(w[j][10], xc.z, acc);
            acc = fmaf(w[j][11], xc.w, acc);
            o2[j] = acc;
        }

        f32x2* dst = reinterpret_cast<f32x2*>(
            out + (size_t)row * OUT_CH + chan);
        __builtin_nontemporal_store(o2, dst);
    }
}

extern "C" void kernel_launch(void* const* d_in, const int* in_sizes, int n_in,
                              void* d_out, int out_size, void* d_ws, size_t ws_size,
                              hipStream_t stream) {
    const float* x      = (const float*)d_in[0];
    const float* weight = (const float*)d_in[1];
    const float* mask   = (const float*)d_in[2];
    const float* bias   = (const float*)d_in[3];
    float* out          = (float*)d_out;

    const int batch = in_sizes[0] / IN_CH;   // 262144
    const int grid  = 768;   // proven best (R4 vs R7 A/B: 768 beats 1280)

    skel_linear_kernel<<<grid, THREADS, 0, stream>>>(x, weight, mask, bias, out, batch);
}